// Round 15
// baseline (432.825 us; speedup 1.0000x reference)
//
#include <hip/hip_runtime.h>
#include <cstdint>
#include <cstddef>

namespace {

constexpr int N_NODES = 100000;
constexpr int N_EDGES = 1600000;
constexpr int NUM_GRAPHS = 128;
constexpr int F = 128;
constexpr float BN_EPS = 1e-5f;

// bucket sort params: 196 buckets x 512 nodes; 400 chunks x 4000 edges
constexpr int W_BUCK = 512;
constexpr int NBUCK = (N_NODES + W_BUCK - 1) / W_BUCK;  // 196
constexpr int CB = 400;
constexpr int CHUNK = N_EDGES / CB;                      // 4000

typedef float f32x4 __attribute__((ext_vector_type(4)));
typedef float f32x2 __attribute__((ext_vector_type(2)));
typedef short s16x8 __attribute__((ext_vector_type(8)));
typedef unsigned char uchar;
union B8 { uint4 u; s16x8 s; };

__device__ inline ushort f2bf(float x) {         // RNE fp32 -> bf16
    uint u = __float_as_uint(x);
    u += 0x7fffu + ((u >> 16) & 1u);
    return (ushort)(u >> 16);
}
__device__ inline float bf2f(ushort s) { return __uint_as_float(((uint)s) << 16); }
__device__ inline uint pack2(float lo, float hi) {
    return (uint)f2bf(lo) | ((uint)f2bf(hi) << 16);
}
__device__ inline float bflo(uint u) { return __uint_as_float(u << 16); }
__device__ inline float bfhi(uint u) { return __uint_as_float(u & 0xffff0000u); }

// accumulate 4 fp8 (one u32) into a[0..3] via HW cvt
__device__ inline void acc4f8(float* a, uint u) {
    f32x2 lo = __builtin_amdgcn_cvt_pk_f32_fp8((int)u, false);
    f32x2 hi = __builtin_amdgcn_cvt_pk_f32_fp8((int)u, true);
    a[0] += lo[0]; a[1] += lo[1]; a[2] += hi[0]; a[3] += hi[1];
}

// ---- CSR-by-dst via 2-level bucket sort (no global atomics) -----------------

__global__ void __launch_bounds__(256) k_histA(const int* __restrict__ ei,
                                               int* __restrict__ gcount) {
    __shared__ int bins[NBUCK];
    int t = threadIdx.x;
    for (int i = t; i < NBUCK; i += 256) bins[i] = 0;
    __syncthreads();
    int e0 = blockIdx.x * CHUNK;
    for (int i = t; i < CHUNK; i += 256)
        atomicAdd(&bins[ei[N_EDGES + e0 + i] >> 9], 1);
    __syncthreads();
    for (int i = t; i < NBUCK; i += 256) gcount[i * CB + blockIdx.x] = bins[i];
}

__global__ void __launch_bounds__(512) k_scanA(int* __restrict__ g,
                                               int* __restrict__ bsum) {
    __shared__ int tmp[512];
    int b = blockIdx.x, t = threadIdx.x;
    int v = (t < CB) ? g[b * CB + t] : 0;
    tmp[t] = v;
    __syncthreads();
    #pragma unroll
    for (int d = 1; d < 512; d <<= 1) {
        int u = (t >= d) ? tmp[t - d] : 0;
        __syncthreads();
        tmp[t] += u;
        __syncthreads();
    }
    if (t < CB) g[b * CB + t] = tmp[t] - v;   // local exclusive prefix
    if (t == 511) bsum[b] = tmp[511];         // bucket total
}

__global__ void __launch_bounds__(256) k_scanB(int* __restrict__ bsum) {
    __shared__ int tmp[256];
    int t = threadIdx.x;
    int v = (t < NBUCK) ? bsum[t] : 0;
    tmp[t] = v;
    __syncthreads();
    #pragma unroll
    for (int d = 1; d < 256; d <<= 1) {
        int u = (t >= d) ? tmp[t - d] : 0;
        __syncthreads();
        tmp[t] += u;
        __syncthreads();
    }
    if (t < NBUCK) bsum[t] = tmp[t] - v;      // bucket exclusive prefix
}

__global__ void __launch_bounds__(256) k_part(const int* __restrict__ ei,
                                              const int* __restrict__ gloc,
                                              const int* __restrict__ bsum,
                                              uint* __restrict__ epk) {
    __shared__ int cur[NBUCK];
    int t = threadIdx.x;
    for (int i = t; i < NBUCK; i += 256)
        cur[i] = gloc[i * CB + blockIdx.x] + bsum[i];
    __syncthreads();
    int e0 = blockIdx.x * CHUNK;
    for (int i = t; i < CHUNK; i += 256) {
        int d = ei[N_EDGES + e0 + i];
        int s = ei[e0 + i];
        int p = atomicAdd(&cur[d >> 9], 1);
        epk[p] = ((uint)s << 9) | (uint)(d & 511);
    }
}

__global__ void __launch_bounds__(512) k_rank(const uint* __restrict__ epk,
                                              const int* __restrict__ bsum,
                                              int* __restrict__ offs,
                                              int* __restrict__ ssrc) {
    __shared__ int dcnt[W_BUCK];
    __shared__ int tmp[W_BUCK];
    __shared__ int cur[W_BUCK];
    int b = blockIdx.x, t = threadIdx.x;
    dcnt[t] = 0;
    __syncthreads();
    int s0 = bsum[b];
    int s1 = (b + 1 < NBUCK) ? bsum[b + 1] : N_EDGES;
    for (int i = s0 + t; i < s1; i += 512)
        atomicAdd(&dcnt[epk[i] & 511u], 1);
    __syncthreads();
    int v = dcnt[t];
    tmp[t] = v;
    __syncthreads();
    #pragma unroll
    for (int d = 1; d < 512; d <<= 1) {
        int u = (t >= d) ? tmp[t - d] : 0;
        __syncthreads();
        tmp[t] += u;
        __syncthreads();
    }
    int start = s0 + tmp[t] - v;               // exclusive prefix
    int node = b * W_BUCK + t;
    if (node <= N_NODES) offs[node] = start;   // node==N_NODES: writes offs end
    cur[t] = start;
    __syncthreads();
    for (int i = s0 + t; i < s1; i += 512) {
        uint u = epk[i];
        int p = atomicAdd(&cur[u & 511u], 1);
        ssrc[p] = (int)(u >> 9);
    }
}

// ---- graph segment boundaries (batch is sorted) ----------------------------

__global__ void k_bound(const int* __restrict__ batch, int* __restrict__ gstart) {
    int i = blockIdx.x * 256 + threadIdx.x;
    if (i >= N_NODES) return;
    int b = batch[i];
    if (i == 0) {
        for (int g = 0; g <= b; ++g) gstart[g] = 0;
    } else {
        int p = batch[i - 1];
        if (p != b) for (int g = p + 1; g <= b; ++g) gstart[g] = i;
    }
    if (i == N_NODES - 1) {
        for (int g = b + 1; g <= NUM_GRAPHS; ++g) gstart[g] = N_NODES;
    }
}

// ---- weight packs -----------------------------------------------------------

// layer 2: Wcat[f][0:128]=W2l[f][:], Wcat[f][128:256]=W2r[f][:], bf16
__global__ void k_packbf(const float* __restrict__ Wl, const float* __restrict__ Wr,
                         ushort* __restrict__ Wcat) {
    int i = blockIdx.x * 256 + threadIdx.x;    // 16384 exact
    int f = i >> 7, k = i & 127;
    Wcat[f * 256 + k]       = f2bf(Wl[i]);
    Wcat[f * 256 + 128 + k] = f2bf(Wr[i]);
}

// layer 1: Wcat1[f][32] bf16: k<8 -> W1r[f][k], 8..15 -> W1l[f][k-8], rest 0
__global__ void k_packbf1(const float* __restrict__ W1l, const float* __restrict__ W1r,
                          ushort* __restrict__ Wcat1) {
    int i = blockIdx.x * 256 + threadIdx.x;    // 4096 exact
    int f = i >> 5, k = i & 31;
    float v = (k < 8) ? W1r[f * 8 + k] : ((k < 16) ? W1l[f * 8 + (k - 8)] : 0.f);
    Wcat1[i] = f2bf(v);
}

// ---- layer 1 ---------------------------------------------------------------

// xa[n][32] bf16 = [x[n] (8) | mean_j x[src] (8) | zeros (16)]  — one 64B line
__global__ void k_agg1(const float* __restrict__ x, const int* __restrict__ offs,
                       const int* __restrict__ ssrc, ushort* __restrict__ xa) {
    int n = blockIdx.x * 256 + threadIdx.x;
    if (n >= N_NODES) return;
    int s0 = offs[n], s1 = offs[n + 1];
    float a0=0,a1=0,a2=0,a3=0,a4=0,a5=0,a6=0,a7=0;
    int j = s0;
    for (; j + 3 < s1; j += 4) {               // 8 gathers in flight
        int sa = ssrc[j], sb = ssrc[j+1], sc = ssrc[j+2], sd = ssrc[j+3];
        const float4* pa = (const float4*)(x + (size_t)sa * 8);
        const float4* pb = (const float4*)(x + (size_t)sb * 8);
        const float4* pc = (const float4*)(x + (size_t)sc * 8);
        const float4* pd = (const float4*)(x + (size_t)sd * 8);
        float4 va0 = pa[0], va1 = pa[1], vb0 = pb[0], vb1 = pb[1];
        float4 vc0 = pc[0], vc1 = pc[1], vd0 = pd[0], vd1 = pd[1];
        a0 += (va0.x + vb0.x) + (vc0.x + vd0.x);
        a1 += (va0.y + vb0.y) + (vc0.y + vd0.y);
        a2 += (va0.z + vb0.z) + (vc0.z + vd0.z);
        a3 += (va0.w + vb0.w) + (vc0.w + vd0.w);
        a4 += (va1.x + vb1.x) + (vc1.x + vd1.x);
        a5 += (va1.y + vb1.y) + (vc1.y + vd1.y);
        a6 += (va1.z + vb1.z) + (vc1.z + vd1.z);
        a7 += (va1.w + vb1.w) + (vc1.w + vd1.w);
    }
    for (; j < s1; ++j) {
        const float4* xp = (const float4*)(x + (size_t)ssrc[j] * 8);
        float4 b0 = xp[0], b1 = xp[1];
        a0+=b0.x; a1+=b0.y; a2+=b0.z; a3+=b0.w;
        a4+=b1.x; a5+=b1.y; a6+=b1.z; a7+=b1.w;
    }
    int dg = s1 - s0;
    float inv = 1.0f / (float)(dg > 1 ? dg : 1);
    const float4* xp = (const float4*)(x + (size_t)n * 8);
    float4 x0 = xp[0], x1v = xp[1];
    ushort* row = xa + (size_t)n * 32;
    uint4 o0 = {pack2(x0.x, x0.y), pack2(x0.z, x0.w), pack2(x1v.x, x1v.y), pack2(x1v.z, x1v.w)};
    uint4 o1 = {pack2(a0*inv, a1*inv), pack2(a2*inv, a3*inv),
                pack2(a4*inv, a5*inv), pack2(a6*inv, a7*inv)};
    uint4 z = {0u, 0u, 0u, 0u};
    *(uint4*)(row)      = o0;
    *(uint4*)(row + 8)  = o1;
    *(uint4*)(row + 16) = z;
    *(uint4*)(row + 24) = z;
}

// h1bf = bf16(xa @ Wcat1^T + b1) via one MFMA per f-tile; fp32 BN stats fused.
__global__ void __launch_bounds__(256) k_lin1(
        const ushort* __restrict__ xa, const ushort* __restrict__ Wcat1,
        const float* __restrict__ b1, ushort* __restrict__ h1bf,
        float* __restrict__ stats) {
    __shared__ ushort sOut[64 * 140];          // stride 140: 4-quad conflict-free
    __shared__ float sred[256];
    int tid = threadIdx.x;
    int wave = tid >> 6, lane = tid & 63;
    int quad = lane >> 4, l16 = lane & 15;
    int n0 = blockIdx.x * 64;

    int node = n0 + wave * 16 + l16;
    int cn = (node < N_NODES) ? node : N_NODES - 1;  // clamp; stores masked below
    B8 ta;
    ta.u = *(const uint4*)(xa + (size_t)cn * 32 + quad * 8);

    #pragma unroll
    for (int nt = 0; nt < 8; ++nt) {
        int fb = nt * 16 + l16;
        B8 tb;
        tb.u = *(const uint4*)(Wcat1 + fb * 32 + quad * 8);
        f32x4 acc = {0.f, 0.f, 0.f, 0.f};
        acc = __builtin_amdgcn_mfma_f32_16x16x32_bf16(ta.s, tb.s, acc, 0, 0, 0);
        float bb = b1[fb];
        #pragma unroll
        for (int r = 0; r < 4; ++r) {
            int row = wave * 16 + quad * 4 + r;
            sOut[row * 140 + fb] = f2bf(acc[r] + bb);
        }
    }
    __syncthreads();

    #pragma unroll
    for (int p = 0; p < 4; ++p) {
        int row = p * 16 + (tid >> 4);
        int nd = n0 + row;
        if (nd < N_NODES) {
            int c0 = (tid & 15) * 8;
            uint4 v = *(const uint4*)&sOut[row * 140 + c0];
            *(uint4*)(h1bf + (size_t)nd * F + c0) = v;
        }
    }

    int f = tid & 127, half = tid >> 7;
    float s = 0.f, s2 = 0.f;
    for (int r = half * 32; r < half * 32 + 32; ++r) {
        if (n0 + r >= N_NODES) break;
        float v = bf2f(sOut[r * 140 + f]);
        s += v; s2 += v * v;
    }
    if (half) { sred[f] = s; sred[128 + f] = s2; }
    __syncthreads();
    if (!half) {
        s += sred[f]; s2 += sred[128 + f];
        atomicAdd(&stats[f], s);
        atomicAdd(&stats[F + f], s2);
    }
}

__global__ void k_bnfin(const float* __restrict__ stats, const float* __restrict__ gamma,
                        const float* __restrict__ beta, float* __restrict__ scsh) {
    int f = threadIdx.x;
    float mu  = stats[f] * (1.0f / N_NODES);
    float var = stats[F + f] * (1.0f / N_NODES) - mu * mu;
    float sc  = gamma[f] * rsqrtf(var + BN_EPS);
    scsh[f] = sc;
    scsh[F + f] = beta[f] - mu * sc;
}

// x1bf = bf16(relu(scale*h1 + shift));  x1f8 = fp8_e4m3(same) for the gather
__global__ void k_bnrelu(const ushort* __restrict__ h, const float* __restrict__ scsh,
                         ushort* __restrict__ x1bf, uchar* __restrict__ x1f8) {
    int i = blockIdx.x * 256 + threadIdx.x;      // N*128/8 = 1.6M exact
    int base = i * 8;
    int f = base & (F - 1);
    float4 sc0 = *(const float4*)(scsh + f);
    float4 sc1 = *(const float4*)(scsh + f + 4);
    float4 sh0 = *(const float4*)(scsh + F + f);
    float4 sh1 = *(const float4*)(scsh + F + f + 4);
    uint4 hv = *(const uint4*)(h + base);
    float v0 = fmaxf(0.f, bflo(hv.x)*sc0.x + sh0.x);
    float v1 = fmaxf(0.f, bfhi(hv.x)*sc0.y + sh0.y);
    float v2 = fmaxf(0.f, bflo(hv.y)*sc0.z + sh0.z);
    float v3 = fmaxf(0.f, bfhi(hv.y)*sc0.w + sh0.w);
    float v4 = fmaxf(0.f, bflo(hv.z)*sc1.x + sh1.x);
    float v5 = fmaxf(0.f, bfhi(hv.z)*sc1.y + sh1.y);
    float v6 = fmaxf(0.f, bflo(hv.w)*sc1.z + sh1.z);
    float v7 = fmaxf(0.f, bfhi(hv.w)*sc1.w + sh1.w);
    uint4 o = {pack2(v0,v1), pack2(v2,v3), pack2(v4,v5), pack2(v6,v7)};
    *(uint4*)(x1bf + base) = o;
    int p0 = __builtin_amdgcn_cvt_pk_fp8_f32(v0, v1, 0, false);
    p0     = __builtin_amdgcn_cvt_pk_fp8_f32(v2, v3, p0, true);
    int p1 = __builtin_amdgcn_cvt_pk_fp8_f32(v4, v5, 0, false);
    p1     = __builtin_amdgcn_cvt_pk_fp8_f32(v6, v7, p1, true);
    uint2 o8 = {(uint)p0, (uint)p1};
    *(uint2*)(x1f8 + base) = o8;
}

// ---- layer 2 ---------------------------------------------------------------

// agg2bf[n][f] = bf16(mean over in-edges of fp8 x1f8[src][f]); 8 thr x 16B/node
__global__ void __launch_bounds__(256) k_agg2(
        const uchar* __restrict__ x1f8, const int* __restrict__ offs,
        const int* __restrict__ ssrc, ushort* __restrict__ agg2bf) {
    int t = threadIdx.x;
    int n = blockIdx.x * 32 + (t >> 3);        // 32 nodes/block, N%32==0
    int c16 = (t & 7) * 16;                    // 16 features per thread
    int s0 = offs[n], s1 = offs[n + 1];
    float acc[16];
    #pragma unroll
    for (int i = 0; i < 16; ++i) acc[i] = 0.f;
    int j = s0;
    for (; j + 3 < s1; j += 4) {               // 4 gathers in flight
        int sa = ssrc[j], sb = ssrc[j+1], sc = ssrc[j+2], sd = ssrc[j+3];
        uint4 va = *(const uint4*)(x1f8 + (size_t)sa * F + c16);
        uint4 vb = *(const uint4*)(x1f8 + (size_t)sb * F + c16);
        uint4 vc = *(const uint4*)(x1f8 + (size_t)sc * F + c16);
        uint4 vd = *(const uint4*)(x1f8 + (size_t)sd * F + c16);
        acc4f8(acc,      va.x); acc4f8(acc + 4,  va.y);
        acc4f8(acc + 8,  va.z); acc4f8(acc + 12, va.w);
        acc4f8(acc,      vb.x); acc4f8(acc + 4,  vb.y);
        acc4f8(acc + 8,  vb.z); acc4f8(acc + 12, vb.w);
        acc4f8(acc,      vc.x); acc4f8(acc + 4,  vc.y);
        acc4f8(acc + 8,  vc.z); acc4f8(acc + 12, vc.w);
        acc4f8(acc,      vd.x); acc4f8(acc + 4,  vd.y);
        acc4f8(acc + 8,  vd.z); acc4f8(acc + 12, vd.w);
    }
    for (; j < s1; ++j) {
        uint4 v = *(const uint4*)(x1f8 + (size_t)ssrc[j] * F + c16);
        acc4f8(acc,      v.x); acc4f8(acc + 4,  v.y);
        acc4f8(acc + 8,  v.z); acc4f8(acc + 12, v.w);
    }
    int dg = s1 - s0;
    float inv = 1.0f / (float)(dg > 1 ? dg : 1);
    uint4 o0 = {pack2(acc[0]*inv,  acc[1]*inv),  pack2(acc[2]*inv,  acc[3]*inv),
                pack2(acc[4]*inv,  acc[5]*inv),  pack2(acc[6]*inv,  acc[7]*inv)};
    uint4 o1 = {pack2(acc[8]*inv,  acc[9]*inv),  pack2(acc[10]*inv, acc[11]*inv),
                pack2(acc[12]*inv, acc[13]*inv), pack2(acc[14]*inv, acc[15]*inv)};
    ushort* dst = agg2bf + (size_t)n * F + c16;
    *(uint4*)(dst)     = o0;
    *(uint4*)(dst + 8) = o1;
}

// h2 = agg2 @ W2l^T + b2 + x1 @ W2r^T via bf16 MFMA.
// 512-thread blocks (8 waves) share one 64KB swizzled B-LDS -> 16 waves/CU.
// Per wave: 2 node-tiles, A-frags in regs (16 loads in flight), loop over all
// 8 f-tiles with ds_read:MFMA 1:1. Swizzle verified 8-phase conflict-free.
__device__ inline int gSw(int f, int j) { return (f << 5) | ((j + f) & 31); }

__global__ void __launch_bounds__(512, 4) k_lin2(
        const ushort* __restrict__ agg2bf, const ushort* __restrict__ x1bf,
        const ushort* __restrict__ Wcat, const float* __restrict__ b2,
        ushort* __restrict__ h2bf, float* __restrict__ stats) {
    __shared__ ushort sB[4096 * 8];            // 64 KB, swizzled granules
    int tid = threadIdx.x;
    int wave = tid >> 6, lane = tid & 63;
    int quad = lane >> 4, l16 = lane & 15;

    // stage Wcat -> LDS (coalesced global; swizzled conflict-free LDS writes)
    #pragma unroll
    for (int it = 0; it < 8; ++it) {
        int c = it * 512 + tid;                // Wcat 16B-granule index
        int f = c >> 5, j = c & 31;
        uint4 v = *(const uint4*)(Wcat + (size_t)c * 8);
        *(uint4*)&sB[gSw(f, j) * 8] = v;
    }
    float bb[8];
    #pragma unroll
    for (int ft = 0; ft < 8; ++ft) bb[ft] = b2[ft * 16 + l16];
    __syncthreads();

    float ss[8], sq[8];
    #pragma unroll
    for (int i = 0; i < 8; ++i) { ss[i] = 0.f; sq[i] = 0.f; }

    int nbase = blockIdx.x * 256 + wave * 32;  // 2 tiles of 16 per wave

    s16x8 aA[8], aB[8];
    auto loadA = [&](s16x8* a, int nb) {
        int an = nb + l16;
        if (an >= N_NODES) an = N_NODES - 1;   // clamp; stores masked below
        #pragma unroll
        for (int ks = 0; ks < 8; ++ks) {       // 8 independent 16B loads
            const ushort* src = (ks < 4) ? agg2bf : x1bf;
            B8 tm;
            tm.u = *(const uint4*)(src + (size_t)an * F + (ks & 3) * 32 + quad * 8);
            a[ks] = tm.s;
        }
    };
    auto compute = [&](s16x8* a, int nb) {
        #pragma unroll
        for (int ft = 0; ft < 8; ++ft) {
            int f = ft * 16 + l16;
            f32x4 acc = {0.f, 0.f, 0.f, 0.f};
            #pragma unroll
            for (int ks = 0; ks < 8; ++ks) {
                B8 tb;
                tb.u = *(const uint4*)&sB[gSw(f, (ks << 2) + quad) * 8];
                acc = __builtin_amdgcn_mfma_f32_16x16x32_bf16(a[ks], tb.s, acc, 0, 0, 0);
            }
            #pragma unroll
            for (int r = 0; r < 4; ++r) {      // C: row=quad*4+r (node), col=f
                int node = nb + quad * 4 + r;
                if (node < N_NODES) {
                    float v = acc[r] + bb[ft];
                    h2bf[(size_t)node * F + f] = f2bf(v);
                    ss[ft] += v; sq[ft] += v * v;
                }
            }
        }
    };

    loadA(aA, nbase);
    loadA(aB, nbase + 16);
    compute(aA, nbase);
    compute(aB, nbase + 16);

    // stats: quad-reduce -> per-wave LDS arena (sB reuse) -> 1 atomic/f/block
    #pragma unroll
    for (int i = 0; i < 8; ++i) {
        ss[i] += __shfl_xor(ss[i], 16); ss[i] += __shfl_xor(ss[i], 32);
        sq[i] += __shfl_xor(sq[i], 16); sq[i] += __shfl_xor(sq[i], 32);
    }
    __syncthreads();                           // all sB reads done
    float* sred = (float*)sB;                  // [wave][256]: [s(128) | s2(128)]
    if (quad == 0) {
        #pragma unroll
        for (int ft = 0; ft < 8; ++ft) {
            sred[wave * 256 + ft * 16 + l16]       = ss[ft];
            sred[wave * 256 + 128 + ft * 16 + l16] = sq[ft];
        }
    }
    __syncthreads();
    if (tid < 256) {
        float s = 0.f;
        #pragma unroll
        for (int w2 = 0; w2 < 8; ++w2) s += sred[w2 * 256 + tid];
        atomicAdd(&stats[tid], s);             // stats: [s(128) | s2(128)]
    }
}

// ---- pooling ---------------------------------------------------------------

__global__ void k_pool(const ushort* __restrict__ x1bf, const ushort* __restrict__ h2bf,
                       const float* __restrict__ scsh2, const int* __restrict__ batch,
                       float* __restrict__ outacc) {
    int f = threadIdx.x;
    int n0 = blockIdx.x * 128;
    int n1 = min(n0 + 128, N_NODES);
    float sc = scsh2[f], sh = scsh2[F + f];
    float acc = 0.f;
    int curg = batch[n0];
    for (int n = n0; n < n1; ++n) {
        int g = batch[n];
        if (g != curg) {
            atomicAdd(&outacc[curg * F + f], acc);
            acc = 0.f; curg = g;
        }
        float v1 = bf2f(x1bf[(size_t)n * F + f]);
        float v2 = fmaxf(0.f, bf2f(h2bf[(size_t)n * F + f]) * sc + sh);
        acc += v1 + v2;
    }
    atomicAdd(&outacc[curg * F + f], acc);
}

__global__ void k_out(const float* __restrict__ outacc, const int* __restrict__ gstart,
                      float* __restrict__ out) {
    int i = blockIdx.x * 256 + threadIdx.x;
    if (i >= NUM_GRAPHS * F) return;
    int g = i >> 7;
    int c = gstart[g + 1] - gstart[g];
    out[i] = outacc[i] / (float)(c > 1 ? c : 1);
}

}  // namespace

extern "C" void kernel_launch(void* const* d_in, const int* in_sizes, int n_in,
                              void* d_out, int out_size, void* d_ws, size_t ws_size,
                              hipStream_t stream) {
    const float* x     = (const float*)d_in[0];
    const int*   ei    = (const int*)d_in[1];    // [2, E]: row0 = src, row1 = dst
    const int*   batch = (const int*)d_in[2];
    const float* W1l   = (const float*)d_in[3];
    const float* b1    = (const float*)d_in[4];
    const float* W1r   = (const float*)d_in[5];
    const float* g1    = (const float*)d_in[6];
    const float* be1   = (const float*)d_in[7];
    const float* W2l   = (const float*)d_in[8];
    const float* b2    = (const float*)d_in[9];
    const float* W2r   = (const float*)d_in[10];
    const float* g2    = (const float*)d_in[11];
    const float* be2   = (const float*)d_in[12];
    float* out = (float*)d_out;

    char* w = (char*)d_ws;
    size_t o = 0;
    auto alloc = [&](size_t bytes) {
        void* p = w + o;
        o += (bytes + 511) & ~(size_t)511;
        return p;
    };
    int*    offs   = (int*)alloc((size_t)(N_NODES + 1) * 4);
    int*    gcount = (int*)alloc((size_t)NBUCK * CB * 4);
    int*    bsum   = (int*)alloc((size_t)NBUCK * 4);
    int*    ssrc   = (int*)alloc((size_t)N_EDGES * 4);
    uint*   epk    = (uint*)alloc((size_t)N_EDGES * 4);
    int*    gstart = (int*)alloc((NUM_GRAPHS + 1) * 4);
    float*  stats  = (float*)alloc(512 * 4);   // [s1,s1sq | s2,s2sq]
    float*  scsh   = (float*)alloc(512 * 4);   // [sc1,sh1 | sc2,sh2]
    ushort* Wcat   = (ushort*)alloc((size_t)F * 256 * 2);
    ushort* Wcat1  = (ushort*)alloc((size_t)F * 32 * 2);
    float*  outacc = (float*)alloc((size_t)NUM_GRAPHS * F * 4);
    ushort* xa     = (ushort*)alloc((size_t)N_NODES * 32 * 2);
    ushort* h1bf   = (ushort*)alloc((size_t)N_NODES * F * 2);
    ushort* x1bf   = (ushort*)alloc((size_t)N_NODES * F * 2);
    uchar*  x1f8   = (uchar*)alloc((size_t)N_NODES * F);
    ushort* agg2bf = (ushort*)alloc((size_t)N_NODES * F * 2);
    ushort* h2bf   = (ushort*)alloc((size_t)N_NODES * F * 2);

    hipMemsetAsync(stats,  0, 512 * 4, stream);
    hipMemsetAsync(outacc, 0, (size_t)NUM_GRAPHS * F * 4, stream);

    // CSR-by-dst: chunk bucket hist -> hierarchical scan -> partition -> rank
    k_histA<<<CB, 256, 0, stream>>>(ei, gcount);
    k_scanA<<<NBUCK, 512, 0, stream>>>(gcount, bsum);
    k_scanB<<<1, 256, 0, stream>>>(bsum);
    k_part <<<CB, 256, 0, stream>>>(ei, gcount, bsum, epk);
    k_rank <<<NBUCK, 512, 0, stream>>>(epk, bsum, offs, ssrc);
    k_bound<<<(N_NODES + 255) / 256, 256, 0, stream>>>(batch, gstart);
    k_packbf <<<64, 256, 0, stream>>>(W2l, W2r, Wcat);
    k_packbf1<<<16, 256, 0, stream>>>(W1l, W1r, Wcat1);

    // layer 1 (bf16 + MFMA; stats fused into k_lin1)
    k_agg1  <<<(N_NODES + 255) / 256, 256, 0, stream>>>(x, offs, ssrc, xa);
    k_lin1  <<<(N_NODES + 63) / 64, 256, 0, stream>>>(xa, Wcat1, b1, h1bf, stats);
    k_bnfin <<<1, 128, 0, stream>>>(stats, g1, be1, scsh);
    k_bnrelu<<<(N_NODES * F / 8) / 256, 256, 0, stream>>>(h1bf, scsh, x1bf, x1f8);

    // layer 2 (fp8 gather -> fp32 accum -> bf16 MFMA; B in swizzled LDS)
    k_agg2  <<<N_NODES / 32, 256, 0, stream>>>(x1f8, offs, ssrc, agg2bf);
    k_lin2  <<<(N_NODES + 255) / 256, 512, 0, stream>>>(agg2bf, x1bf, Wcat, b2,
                                                        h2bf, stats + 256);
    k_bnfin <<<1, 128, 0, stream>>>(stats + 256, g2, be2, scsh + 256);

    // residual + pool
    k_pool<<<(N_NODES + 127) / 128, 128, 0, stream>>>(x1bf, h2bf, scsh + 256, batch, outacc);
    k_out <<<(NUM_GRAPHS * F + 255) / 256, 256, 0, stream>>>(outacc, gstart, out);
}

// Round 16
// 372.387 us; speedup vs baseline: 1.1623x; 1.1623x over previous
//
#include <hip/hip_runtime.h>
#include <cstdint>
#include <cstddef>

namespace {

constexpr int N_NODES = 100000;
constexpr int N_EDGES = 1600000;
constexpr int NUM_GRAPHS = 128;
constexpr int F = 128;
constexpr float BN_EPS = 1e-5f;

// bucket sort params: 196 buckets x 512 nodes; 400 chunks x 4000 edges
constexpr int W_BUCK = 512;
constexpr int NBUCK = (N_NODES + W_BUCK - 1) / W_BUCK;  // 196
constexpr int CB = 400;
constexpr int CHUNK = N_EDGES / CB;                      // 4000

typedef float f32x4 __attribute__((ext_vector_type(4)));
typedef float f32x2 __attribute__((ext_vector_type(2)));
typedef short s16x8 __attribute__((ext_vector_type(8)));
typedef unsigned char uchar;
union B8 { uint4 u; s16x8 s; };

__device__ inline ushort f2bf(float x) {         // RNE fp32 -> bf16
    uint u = __float_as_uint(x);
    u += 0x7fffu + ((u >> 16) & 1u);
    return (ushort)(u >> 16);
}
__device__ inline float bf2f(ushort s) { return __uint_as_float(((uint)s) << 16); }
__device__ inline uint pack2(float lo, float hi) {
    return (uint)f2bf(lo) | ((uint)f2bf(hi) << 16);
}
__device__ inline float bflo(uint u) { return __uint_as_float(u << 16); }
__device__ inline float bfhi(uint u) { return __uint_as_float(u & 0xffff0000u); }

// accumulate 4 fp8 (one u32) into a[0..3] via HW cvt
__device__ inline void acc4f8(float* a, uint u) {
    f32x2 lo = __builtin_amdgcn_cvt_pk_f32_fp8((int)u, false);
    f32x2 hi = __builtin_amdgcn_cvt_pk_f32_fp8((int)u, true);
    a[0] += lo[0]; a[1] += lo[1]; a[2] += hi[0]; a[3] += hi[1];
}

// ---- CSR-by-dst via 2-level bucket sort (no global atomics) -----------------

__global__ void __launch_bounds__(256) k_histA(const int* __restrict__ ei,
                                               int* __restrict__ gcount) {
    __shared__ int bins[NBUCK];
    int t = threadIdx.x;
    for (int i = t; i < NBUCK; i += 256) bins[i] = 0;
    __syncthreads();
    int e0 = blockIdx.x * CHUNK;
    for (int i = t; i < CHUNK; i += 256)
        atomicAdd(&bins[ei[N_EDGES + e0 + i] >> 9], 1);
    __syncthreads();
    for (int i = t; i < NBUCK; i += 256) gcount[i * CB + blockIdx.x] = bins[i];
}

__global__ void __launch_bounds__(512) k_scanA(int* __restrict__ g,
                                               int* __restrict__ bsum) {
    __shared__ int tmp[512];
    int b = blockIdx.x, t = threadIdx.x;
    int v = (t < CB) ? g[b * CB + t] : 0;
    tmp[t] = v;
    __syncthreads();
    #pragma unroll
    for (int d = 1; d < 512; d <<= 1) {
        int u = (t >= d) ? tmp[t - d] : 0;
        __syncthreads();
        tmp[t] += u;
        __syncthreads();
    }
    if (t < CB) g[b * CB + t] = tmp[t] - v;   // local exclusive prefix
    if (t == 511) bsum[b] = tmp[511];         // bucket total
}

__global__ void __launch_bounds__(256) k_scanB(int* __restrict__ bsum) {
    __shared__ int tmp[256];
    int t = threadIdx.x;
    int v = (t < NBUCK) ? bsum[t] : 0;
    tmp[t] = v;
    __syncthreads();
    #pragma unroll
    for (int d = 1; d < 256; d <<= 1) {
        int u = (t >= d) ? tmp[t - d] : 0;
        __syncthreads();
        tmp[t] += u;
        __syncthreads();
    }
    if (t < NBUCK) bsum[t] = tmp[t] - v;      // bucket exclusive prefix
}

__global__ void __launch_bounds__(256) k_part(const int* __restrict__ ei,
                                              const int* __restrict__ gloc,
                                              const int* __restrict__ bsum,
                                              uint* __restrict__ epk) {
    __shared__ int cur[NBUCK];
    int t = threadIdx.x;
    for (int i = t; i < NBUCK; i += 256)
        cur[i] = gloc[i * CB + blockIdx.x] + bsum[i];
    __syncthreads();
    int e0 = blockIdx.x * CHUNK;
    for (int i = t; i < CHUNK; i += 256) {
        int d = ei[N_EDGES + e0 + i];
        int s = ei[e0 + i];
        int p = atomicAdd(&cur[d >> 9], 1);
        epk[p] = ((uint)s << 9) | (uint)(d & 511);
    }
}

__global__ void __launch_bounds__(512) k_rank(const uint* __restrict__ epk,
                                              const int* __restrict__ bsum,
                                              int* __restrict__ offs,
                                              int* __restrict__ ssrc) {
    __shared__ int dcnt[W_BUCK];
    __shared__ int tmp[W_BUCK];
    __shared__ int cur[W_BUCK];
    int b = blockIdx.x, t = threadIdx.x;
    dcnt[t] = 0;
    __syncthreads();
    int s0 = bsum[b];
    int s1 = (b + 1 < NBUCK) ? bsum[b + 1] : N_EDGES;
    for (int i = s0 + t; i < s1; i += 512)
        atomicAdd(&dcnt[epk[i] & 511u], 1);
    __syncthreads();
    int v = dcnt[t];
    tmp[t] = v;
    __syncthreads();
    #pragma unroll
    for (int d = 1; d < 512; d <<= 1) {
        int u = (t >= d) ? tmp[t - d] : 0;
        __syncthreads();
        tmp[t] += u;
        __syncthreads();
    }
    int start = s0 + tmp[t] - v;               // exclusive prefix
    int node = b * W_BUCK + t;
    if (node <= N_NODES) offs[node] = start;   // node==N_NODES: writes offs end
    cur[t] = start;
    __syncthreads();
    for (int i = s0 + t; i < s1; i += 512) {
        uint u = epk[i];
        int p = atomicAdd(&cur[u & 511u], 1);
        ssrc[p] = (int)(u >> 9);
    }
}

// ---- graph segment boundaries (batch is sorted) ----------------------------

__global__ void k_bound(const int* __restrict__ batch, int* __restrict__ gstart) {
    int i = blockIdx.x * 256 + threadIdx.x;
    if (i >= N_NODES) return;
    int b = batch[i];
    if (i == 0) {
        for (int g = 0; g <= b; ++g) gstart[g] = 0;
    } else {
        int p = batch[i - 1];
        if (p != b) for (int g = p + 1; g <= b; ++g) gstart[g] = i;
    }
    if (i == N_NODES - 1) {
        for (int g = b + 1; g <= NUM_GRAPHS; ++g) gstart[g] = N_NODES;
    }
}

// ---- weight packs -----------------------------------------------------------

// layer 2: Wcat[f][0:128]=W2l[f][:], Wcat[f][128:256]=W2r[f][:], bf16
__global__ void k_packbf(const float* __restrict__ Wl, const float* __restrict__ Wr,
                         ushort* __restrict__ Wcat) {
    int i = blockIdx.x * 256 + threadIdx.x;    // 16384 exact
    int f = i >> 7, k = i & 127;
    Wcat[f * 256 + k]       = f2bf(Wl[i]);
    Wcat[f * 256 + 128 + k] = f2bf(Wr[i]);
}

// layer 1: Wcat1[f][32] bf16: k<8 -> W1r[f][k], 8..15 -> W1l[f][k-8], rest 0
__global__ void k_packbf1(const float* __restrict__ W1l, const float* __restrict__ W1r,
                          ushort* __restrict__ Wcat1) {
    int i = blockIdx.x * 256 + threadIdx.x;    // 4096 exact
    int f = i >> 5, k = i & 31;
    float v = (k < 8) ? W1r[f * 8 + k] : ((k < 16) ? W1l[f * 8 + (k - 8)] : 0.f);
    Wcat1[i] = f2bf(v);
}

// ---- layer 1 ---------------------------------------------------------------

// xa[n][32] bf16 = [x[n] (8) | mean_j x[src] (8) | zeros (16)]  — one 64B line
__global__ void k_agg1(const float* __restrict__ x, const int* __restrict__ offs,
                       const int* __restrict__ ssrc, ushort* __restrict__ xa) {
    int n = blockIdx.x * 256 + threadIdx.x;
    if (n >= N_NODES) return;
    int s0 = offs[n], s1 = offs[n + 1];
    float a0=0,a1=0,a2=0,a3=0,a4=0,a5=0,a6=0,a7=0;
    int j = s0;
    for (; j + 3 < s1; j += 4) {               // 8 gathers in flight
        int sa = ssrc[j], sb = ssrc[j+1], sc = ssrc[j+2], sd = ssrc[j+3];
        const float4* pa = (const float4*)(x + (size_t)sa * 8);
        const float4* pb = (const float4*)(x + (size_t)sb * 8);
        const float4* pc = (const float4*)(x + (size_t)sc * 8);
        const float4* pd = (const float4*)(x + (size_t)sd * 8);
        float4 va0 = pa[0], va1 = pa[1], vb0 = pb[0], vb1 = pb[1];
        float4 vc0 = pc[0], vc1 = pc[1], vd0 = pd[0], vd1 = pd[1];
        a0 += (va0.x + vb0.x) + (vc0.x + vd0.x);
        a1 += (va0.y + vb0.y) + (vc0.y + vd0.y);
        a2 += (va0.z + vb0.z) + (vc0.z + vd0.z);
        a3 += (va0.w + vb0.w) + (vc0.w + vd0.w);
        a4 += (va1.x + vb1.x) + (vc1.x + vd1.x);
        a5 += (va1.y + vb1.y) + (vc1.y + vd1.y);
        a6 += (va1.z + vb1.z) + (vc1.z + vd1.z);
        a7 += (va1.w + vb1.w) + (vc1.w + vd1.w);
    }
    for (; j < s1; ++j) {
        const float4* xp = (const float4*)(x + (size_t)ssrc[j] * 8);
        float4 b0 = xp[0], b1 = xp[1];
        a0+=b0.x; a1+=b0.y; a2+=b0.z; a3+=b0.w;
        a4+=b1.x; a5+=b1.y; a6+=b1.z; a7+=b1.w;
    }
    int dg = s1 - s0;
    float inv = 1.0f / (float)(dg > 1 ? dg : 1);
    const float4* xp = (const float4*)(x + (size_t)n * 8);
    float4 x0 = xp[0], x1v = xp[1];
    ushort* row = xa + (size_t)n * 32;
    uint4 o0 = {pack2(x0.x, x0.y), pack2(x0.z, x0.w), pack2(x1v.x, x1v.y), pack2(x1v.z, x1v.w)};
    uint4 o1 = {pack2(a0*inv, a1*inv), pack2(a2*inv, a3*inv),
                pack2(a4*inv, a5*inv), pack2(a6*inv, a7*inv)};
    uint4 z = {0u, 0u, 0u, 0u};
    *(uint4*)(row)      = o0;
    *(uint4*)(row + 8)  = o1;
    *(uint4*)(row + 16) = z;
    *(uint4*)(row + 24) = z;
}

// h1bf = bf16(xa @ Wcat1^T + b1) via one MFMA per f-tile; fp32 BN stats fused.
__global__ void __launch_bounds__(256) k_lin1(
        const ushort* __restrict__ xa, const ushort* __restrict__ Wcat1,
        const float* __restrict__ b1, ushort* __restrict__ h1bf,
        float* __restrict__ stats) {
    __shared__ ushort sOut[64 * 140];          // stride 140: 4-quad conflict-free
    __shared__ float sred[256];
    int tid = threadIdx.x;
    int wave = tid >> 6, lane = tid & 63;
    int quad = lane >> 4, l16 = lane & 15;
    int n0 = blockIdx.x * 64;

    int node = n0 + wave * 16 + l16;
    int cn = (node < N_NODES) ? node : N_NODES - 1;  // clamp; stores masked below
    B8 ta;
    ta.u = *(const uint4*)(xa + (size_t)cn * 32 + quad * 8);

    #pragma unroll
    for (int nt = 0; nt < 8; ++nt) {
        int fb = nt * 16 + l16;
        B8 tb;
        tb.u = *(const uint4*)(Wcat1 + fb * 32 + quad * 8);
        f32x4 acc = {0.f, 0.f, 0.f, 0.f};
        acc = __builtin_amdgcn_mfma_f32_16x16x32_bf16(ta.s, tb.s, acc, 0, 0, 0);
        float bb = b1[fb];
        #pragma unroll
        for (int r = 0; r < 4; ++r) {
            int row = wave * 16 + quad * 4 + r;
            sOut[row * 140 + fb] = f2bf(acc[r] + bb);
        }
    }
    __syncthreads();

    #pragma unroll
    for (int p = 0; p < 4; ++p) {
        int row = p * 16 + (tid >> 4);
        int nd = n0 + row;
        if (nd < N_NODES) {
            int c0 = (tid & 15) * 8;
            uint4 v = *(const uint4*)&sOut[row * 140 + c0];
            *(uint4*)(h1bf + (size_t)nd * F + c0) = v;
        }
    }

    int f = tid & 127, half = tid >> 7;
    float s = 0.f, s2 = 0.f;
    for (int r = half * 32; r < half * 32 + 32; ++r) {
        if (n0 + r >= N_NODES) break;
        float v = bf2f(sOut[r * 140 + f]);
        s += v; s2 += v * v;
    }
    if (half) { sred[f] = s; sred[128 + f] = s2; }
    __syncthreads();
    if (!half) {
        s += sred[f]; s2 += sred[128 + f];
        atomicAdd(&stats[f], s);
        atomicAdd(&stats[F + f], s2);
    }
}

__global__ void k_bnfin(const float* __restrict__ stats, const float* __restrict__ gamma,
                        const float* __restrict__ beta, float* __restrict__ scsh) {
    int f = threadIdx.x;
    float mu  = stats[f] * (1.0f / N_NODES);
    float var = stats[F + f] * (1.0f / N_NODES) - mu * mu;
    float sc  = gamma[f] * rsqrtf(var + BN_EPS);
    scsh[f] = sc;
    scsh[F + f] = beta[f] - mu * sc;
}

// x1bf = bf16(relu(scale*h1 + shift));  x1f8 = fp8_e4m3(same) for the gather
__global__ void k_bnrelu(const ushort* __restrict__ h, const float* __restrict__ scsh,
                         ushort* __restrict__ x1bf, uchar* __restrict__ x1f8) {
    int i = blockIdx.x * 256 + threadIdx.x;      // N*128/8 = 1.6M exact
    int base = i * 8;
    int f = base & (F - 1);
    float4 sc0 = *(const float4*)(scsh + f);
    float4 sc1 = *(const float4*)(scsh + f + 4);
    float4 sh0 = *(const float4*)(scsh + F + f);
    float4 sh1 = *(const float4*)(scsh + F + f + 4);
    uint4 hv = *(const uint4*)(h + base);
    float v0 = fmaxf(0.f, bflo(hv.x)*sc0.x + sh0.x);
    float v1 = fmaxf(0.f, bfhi(hv.x)*sc0.y + sh0.y);
    float v2 = fmaxf(0.f, bflo(hv.y)*sc0.z + sh0.z);
    float v3 = fmaxf(0.f, bfhi(hv.y)*sc0.w + sh0.w);
    float v4 = fmaxf(0.f, bflo(hv.z)*sc1.x + sh1.x);
    float v5 = fmaxf(0.f, bfhi(hv.z)*sc1.y + sh1.y);
    float v6 = fmaxf(0.f, bflo(hv.w)*sc1.z + sh1.z);
    float v7 = fmaxf(0.f, bfhi(hv.w)*sc1.w + sh1.w);
    uint4 o = {pack2(v0,v1), pack2(v2,v3), pack2(v4,v5), pack2(v6,v7)};
    *(uint4*)(x1bf + base) = o;
    int p0 = __builtin_amdgcn_cvt_pk_fp8_f32(v0, v1, 0, false);
    p0     = __builtin_amdgcn_cvt_pk_fp8_f32(v2, v3, p0, true);
    int p1 = __builtin_amdgcn_cvt_pk_fp8_f32(v4, v5, 0, false);
    p1     = __builtin_amdgcn_cvt_pk_fp8_f32(v6, v7, p1, true);
    uint2 o8 = {(uint)p0, (uint)p1};
    *(uint2*)(x1f8 + base) = o8;
}

// ---- layer 2 ---------------------------------------------------------------

// agg2bf[n][f] = bf16(mean over in-edges of fp8 x1f8[src][f]); 8 thr x 16B/node
__global__ void __launch_bounds__(256) k_agg2(
        const uchar* __restrict__ x1f8, const int* __restrict__ offs,
        const int* __restrict__ ssrc, ushort* __restrict__ agg2bf) {
    int t = threadIdx.x;
    int n = blockIdx.x * 32 + (t >> 3);        // 32 nodes/block, N%32==0
    int c16 = (t & 7) * 16;                    // 16 features per thread
    int s0 = offs[n], s1 = offs[n + 1];
    float acc[16];
    #pragma unroll
    for (int i = 0; i < 16; ++i) acc[i] = 0.f;
    int j = s0;
    for (; j + 3 < s1; j += 4) {               // 4 gathers in flight
        int sa = ssrc[j], sb = ssrc[j+1], sc = ssrc[j+2], sd = ssrc[j+3];
        uint4 va = *(const uint4*)(x1f8 + (size_t)sa * F + c16);
        uint4 vb = *(const uint4*)(x1f8 + (size_t)sb * F + c16);
        uint4 vc = *(const uint4*)(x1f8 + (size_t)sc * F + c16);
        uint4 vd = *(const uint4*)(x1f8 + (size_t)sd * F + c16);
        acc4f8(acc,      va.x); acc4f8(acc + 4,  va.y);
        acc4f8(acc + 8,  va.z); acc4f8(acc + 12, va.w);
        acc4f8(acc,      vb.x); acc4f8(acc + 4,  vb.y);
        acc4f8(acc + 8,  vb.z); acc4f8(acc + 12, vb.w);
        acc4f8(acc,      vc.x); acc4f8(acc + 4,  vc.y);
        acc4f8(acc + 8,  vc.z); acc4f8(acc + 12, vc.w);
        acc4f8(acc,      vd.x); acc4f8(acc + 4,  vd.y);
        acc4f8(acc + 8,  vd.z); acc4f8(acc + 12, vd.w);
    }
    for (; j < s1; ++j) {
        uint4 v = *(const uint4*)(x1f8 + (size_t)ssrc[j] * F + c16);
        acc4f8(acc,      v.x); acc4f8(acc + 4,  v.y);
        acc4f8(acc + 8,  v.z); acc4f8(acc + 12, v.w);
    }
    int dg = s1 - s0;
    float inv = 1.0f / (float)(dg > 1 ? dg : 1);
    uint4 o0 = {pack2(acc[0]*inv,  acc[1]*inv),  pack2(acc[2]*inv,  acc[3]*inv),
                pack2(acc[4]*inv,  acc[5]*inv),  pack2(acc[6]*inv,  acc[7]*inv)};
    uint4 o1 = {pack2(acc[8]*inv,  acc[9]*inv),  pack2(acc[10]*inv, acc[11]*inv),
                pack2(acc[12]*inv, acc[13]*inv), pack2(acc[14]*inv, acc[15]*inv)};
    ushort* dst = agg2bf + (size_t)n * F + c16;
    *(uint4*)(dst)     = o0;
    *(uint4*)(dst + 8) = o1;
}

// h2 = agg2 @ W2l^T + b2 + x1 @ W2r^T via bf16 MFMA.
// f-split: block = 128 nodes x 64 features; B-LDS 32 KB (swizzled) -> 4+
// blocks/CU. fhalf interleaved in blockIdx so paired blocks share A in L2.
// Per wave: 2 sequential node-tiles, single a[8] buffer (32 VGPRs — the shape
// the allocator reliably holds), 4 ft-iterations reuse each a[ks].
__device__ inline int gSw(int f, int j) { return (f << 5) | ((j + f) & 31); }

__global__ void __launch_bounds__(256) k_lin2(
        const ushort* __restrict__ agg2bf, const ushort* __restrict__ x1bf,
        const ushort* __restrict__ Wcat, const float* __restrict__ b2,
        ushort* __restrict__ h2bf, float* __restrict__ stats) {
    __shared__ ushort sB[2048 * 8];            // 32 KB, swizzled granules
    int tid = threadIdx.x;
    int wave = tid >> 6, lane = tid & 63;
    int quad = lane >> 4, l16 = lane & 15;
    int fhalf = blockIdx.x & 1;
    int n0 = (blockIdx.x >> 1) * 128;
    int fbase = fhalf * 64;

    // stage this half's Wcat -> LDS (coalesced; swizzled conflict-free writes)
    #pragma unroll
    for (int it = 0; it < 8; ++it) {
        int c = it * 256 + tid;                // local granule: lf = c>>5, j = c&31
        int lf = c >> 5, j = c & 31;
        uint4 v = *(const uint4*)(Wcat + ((size_t)(fbase + lf) * 32 + j) * 8);
        *(uint4*)&sB[gSw(lf, j) * 8] = v;
    }
    float bb[4];
    #pragma unroll
    for (int ft = 0; ft < 4; ++ft) bb[ft] = b2[fbase + ft * 16 + l16];
    __syncthreads();

    float ss[4], sq[4];
    #pragma unroll
    for (int i = 0; i < 4; ++i) { ss[i] = 0.f; sq[i] = 0.f; }

    #pragma unroll 1
    for (int tile = 0; tile < 2; ++tile) {
        int nb = n0 + wave * 32 + tile * 16;
        int an = nb + l16;
        if (an >= N_NODES) an = N_NODES - 1;   // clamp; stores masked below
        s16x8 a[8];
        #pragma unroll
        for (int ks = 0; ks < 8; ++ks) {       // 8 independent 16B loads
            const ushort* src = (ks < 4) ? agg2bf : x1bf;
            B8 tm;
            tm.u = *(const uint4*)(src + (size_t)an * F + (ks & 3) * 32 + quad * 8);
            a[ks] = tm.s;
        }
        #pragma unroll
        for (int ft = 0; ft < 4; ++ft) {
            int lf = ft * 16 + l16;
            f32x4 acc = {0.f, 0.f, 0.f, 0.f};
            #pragma unroll
            for (int ks = 0; ks < 8; ++ks) {
                B8 tb;
                tb.u = *(const uint4*)&sB[gSw(lf, (ks << 2) + quad) * 8];
                acc = __builtin_amdgcn_mfma_f32_16x16x32_bf16(a[ks], tb.s, acc, 0, 0, 0);
            }
            #pragma unroll
            for (int r = 0; r < 4; ++r) {      // C: row=quad*4+r (node), col=f
                int node = nb + quad * 4 + r;
                if (node < N_NODES) {
                    float v = acc[r] + bb[ft];
                    h2bf[(size_t)node * F + fbase + lf] = f2bf(v);
                    ss[ft] += v; sq[ft] += v * v;
                }
            }
        }
    }

    // reduce across the 4 quads (same f), then one atomic per f per block
    #pragma unroll
    for (int i = 0; i < 4; ++i) {
        ss[i] += __shfl_xor(ss[i], 16); ss[i] += __shfl_xor(ss[i], 32);
        sq[i] += __shfl_xor(sq[i], 16); sq[i] += __shfl_xor(sq[i], 32);
    }
    if (quad == 0) {
        #pragma unroll
        for (int ft = 0; ft < 4; ++ft) {
            int fg = fbase + ft * 16 + l16;
            atomicAdd(&stats[fg], ss[ft]);
            atomicAdd(&stats[F + fg], sq[ft]);
        }
    }
}

// ---- pooling ---------------------------------------------------------------

__global__ void k_pool(const ushort* __restrict__ x1bf, const ushort* __restrict__ h2bf,
                       const float* __restrict__ scsh2, const int* __restrict__ batch,
                       float* __restrict__ outacc) {
    int f = threadIdx.x;
    int n0 = blockIdx.x * 128;
    int n1 = min(n0 + 128, N_NODES);
    float sc = scsh2[f], sh = scsh2[F + f];
    float acc = 0.f;
    int curg = batch[n0];
    for (int n = n0; n < n1; ++n) {
        int g = batch[n];
        if (g != curg) {
            atomicAdd(&outacc[curg * F + f], acc);
            acc = 0.f; curg = g;
        }
        float v1 = bf2f(x1bf[(size_t)n * F + f]);
        float v2 = fmaxf(0.f, bf2f(h2bf[(size_t)n * F + f]) * sc + sh);
        acc += v1 + v2;
    }
    atomicAdd(&outacc[curg * F + f], acc);
}

__global__ void k_out(const float* __restrict__ outacc, const int* __restrict__ gstart,
                      float* __restrict__ out) {
    int i = blockIdx.x * 256 + threadIdx.x;
    if (i >= NUM_GRAPHS * F) return;
    int g = i >> 7;
    int c = gstart[g + 1] - gstart[g];
    out[i] = outacc[i] / (float)(c > 1 ? c : 1);
}

}  // namespace

extern "C" void kernel_launch(void* const* d_in, const int* in_sizes, int n_in,
                              void* d_out, int out_size, void* d_ws, size_t ws_size,
                              hipStream_t stream) {
    const float* x     = (const float*)d_in[0];
    const int*   ei    = (const int*)d_in[1];    // [2, E]: row0 = src, row1 = dst
    const int*   batch = (const int*)d_in[2];
    const float* W1l   = (const float*)d_in[3];
    const float* b1    = (const float*)d_in[4];
    const float* W1r   = (const float*)d_in[5];
    const float* g1    = (const float*)d_in[6];
    const float* be1   = (const float*)d_in[7];
    const float* W2l   = (const float*)d_in[8];
    const float* b2    = (const float*)d_in[9];
    const float* W2r   = (const float*)d_in[10];
    const float* g2    = (const float*)d_in[11];
    const float* be2   = (const float*)d_in[12];
    float* out = (float*)d_out;

    char* w = (char*)d_ws;
    size_t o = 0;
    auto alloc = [&](size_t bytes) {
        void* p = w + o;
        o += (bytes + 511) & ~(size_t)511;
        return p;
    };
    int*    offs   = (int*)alloc((size_t)(N_NODES + 1) * 4);
    int*    gcount = (int*)alloc((size_t)NBUCK * CB * 4);
    int*    bsum   = (int*)alloc((size_t)NBUCK * 4);
    int*    ssrc   = (int*)alloc((size_t)N_EDGES * 4);
    uint*   epk    = (uint*)alloc((size_t)N_EDGES * 4);
    int*    gstart = (int*)alloc((NUM_GRAPHS + 1) * 4);
    float*  stats  = (float*)alloc(512 * 4);   // [s1,s1sq | s2,s2sq]
    float*  scsh   = (float*)alloc(512 * 4);   // [sc1,sh1 | sc2,sh2]
    ushort* Wcat   = (ushort*)alloc((size_t)F * 256 * 2);
    ushort* Wcat1  = (ushort*)alloc((size_t)F * 32 * 2);
    float*  outacc = (float*)alloc((size_t)NUM_GRAPHS * F * 4);
    ushort* xa     = (ushort*)alloc((size_t)N_NODES * 32 * 2);
    ushort* h1bf   = (ushort*)alloc((size_t)N_NODES * F * 2);
    ushort* x1bf   = (ushort*)alloc((size_t)N_NODES * F * 2);
    uchar*  x1f8   = (uchar*)alloc((size_t)N_NODES * F);
    ushort* agg2bf = (ushort*)alloc((size_t)N_NODES * F * 2);
    ushort* h2bf   = (ushort*)alloc((size_t)N_NODES * F * 2);

    hipMemsetAsync(stats,  0, 512 * 4, stream);
    hipMemsetAsync(outacc, 0, (size_t)NUM_GRAPHS * F * 4, stream);

    // CSR-by-dst: chunk bucket hist -> hierarchical scan -> partition -> rank
    k_histA<<<CB, 256, 0, stream>>>(ei, gcount);
    k_scanA<<<NBUCK, 512, 0, stream>>>(gcount, bsum);
    k_scanB<<<1, 256, 0, stream>>>(bsum);
    k_part <<<CB, 256, 0, stream>>>(ei, gcount, bsum, epk);
    k_rank <<<NBUCK, 512, 0, stream>>>(epk, bsum, offs, ssrc);
    k_bound<<<(N_NODES + 255) / 256, 256, 0, stream>>>(batch, gstart);
    k_packbf <<<64, 256, 0, stream>>>(W2l, W2r, Wcat);
    k_packbf1<<<16, 256, 0, stream>>>(W1l, W1r, Wcat1);

    // layer 1 (bf16 + MFMA; stats fused into k_lin1)
    k_agg1  <<<(N_NODES + 255) / 256, 256, 0, stream>>>(x, offs, ssrc, xa);
    k_lin1  <<<(N_NODES + 63) / 64, 256, 0, stream>>>(xa, Wcat1, b1, h1bf, stats);
    k_bnfin <<<1, 128, 0, stream>>>(stats, g1, be1, scsh);
    k_bnrelu<<<(N_NODES * F / 8) / 256, 256, 0, stream>>>(h1bf, scsh, x1bf, x1f8);

    // layer 2 (fp8 gather -> fp32 accum -> bf16 MFMA; f-split B in LDS)
    k_agg2  <<<N_NODES / 32, 256, 0, stream>>>(x1f8, offs, ssrc, agg2bf);
    k_lin2  <<<2 * ((N_NODES + 127) / 128), 256, 0, stream>>>(agg2bf, x1bf, Wcat,
                                                              b2, h2bf, stats + 256);
    k_bnfin <<<1, 128, 0, stream>>>(stats + 256, g2, be2, scsh + 256);

    // residual + pool
    k_pool<<<(N_NODES + 127) / 128, 128, 0, stream>>>(x1bf, h2bf, scsh + 256, batch, outacc);
    k_out <<<(NUM_GRAPHS * F + 255) / 256, 256, 0, stream>>>(outacc, gstart, out);
}

// Round 17
// 326.805 us; speedup vs baseline: 1.3244x; 1.1395x over previous
//
#include <hip/hip_runtime.h>
#include <cstdint>
#include <cstddef>

namespace {

constexpr int N_NODES = 100000;
constexpr int N_EDGES = 1600000;
constexpr int NUM_GRAPHS = 128;
constexpr int F = 128;
constexpr float BN_EPS = 1e-5f;

// bucket sort params: 196 buckets x 512 nodes; 400 chunks x 4000 edges
constexpr int W_BUCK = 512;
constexpr int NBUCK = (N_NODES + W_BUCK - 1) / W_BUCK;  // 196
constexpr int CB = 400;
constexpr int CHUNK = N_EDGES / CB;                      // 4000

typedef float f32x4 __attribute__((ext_vector_type(4)));
typedef float f32x2 __attribute__((ext_vector_type(2)));
typedef short s16x8 __attribute__((ext_vector_type(8)));
typedef unsigned char uchar;
union B8 { uint4 u; s16x8 s; };

__device__ inline ushort f2bf(float x) {         // RNE fp32 -> bf16
    uint u = __float_as_uint(x);
    u += 0x7fffu + ((u >> 16) & 1u);
    return (ushort)(u >> 16);
}
__device__ inline float bf2f(ushort s) { return __uint_as_float(((uint)s) << 16); }
__device__ inline uint pack2(float lo, float hi) {
    return (uint)f2bf(lo) | ((uint)f2bf(hi) << 16);
}
__device__ inline float bflo(uint u) { return __uint_as_float(u << 16); }
__device__ inline float bfhi(uint u) { return __uint_as_float(u & 0xffff0000u); }

// accumulate 4 fp8 (one u32) into a[0..3] via HW cvt
__device__ inline void acc4f8(float* a, uint u) {
    f32x2 lo = __builtin_amdgcn_cvt_pk_f32_fp8((int)u, false);
    f32x2 hi = __builtin_amdgcn_cvt_pk_f32_fp8((int)u, true);
    a[0] += lo[0]; a[1] += lo[1]; a[2] += hi[0]; a[3] += hi[1];
}

// ---- CSR-by-dst via 2-level bucket sort (no global atomics) -----------------

__global__ void __launch_bounds__(256) k_histA(const int* __restrict__ ei,
                                               int* __restrict__ gcount) {
    __shared__ int bins[NBUCK];
    int t = threadIdx.x;
    for (int i = t; i < NBUCK; i += 256) bins[i] = 0;
    __syncthreads();
    int e0 = blockIdx.x * CHUNK;
    for (int i = t; i < CHUNK; i += 256)
        atomicAdd(&bins[ei[N_EDGES + e0 + i] >> 9], 1);
    __syncthreads();
    for (int i = t; i < NBUCK; i += 256) gcount[i * CB + blockIdx.x] = bins[i];
}

__global__ void __launch_bounds__(512) k_scanA(int* __restrict__ g,
                                               int* __restrict__ bsum) {
    __shared__ int tmp[512];
    int b = blockIdx.x, t = threadIdx.x;
    int v = (t < CB) ? g[b * CB + t] : 0;
    tmp[t] = v;
    __syncthreads();
    #pragma unroll
    for (int d = 1; d < 512; d <<= 1) {
        int u = (t >= d) ? tmp[t - d] : 0;
        __syncthreads();
        tmp[t] += u;
        __syncthreads();
    }
    if (t < CB) g[b * CB + t] = tmp[t] - v;   // local exclusive prefix
    if (t == 511) bsum[b] = tmp[511];         // bucket total
}

__global__ void __launch_bounds__(256) k_scanB(int* __restrict__ bsum) {
    __shared__ int tmp[256];
    int t = threadIdx.x;
    int v = (t < NBUCK) ? bsum[t] : 0;
    tmp[t] = v;
    __syncthreads();
    #pragma unroll
    for (int d = 1; d < 256; d <<= 1) {
        int u = (t >= d) ? tmp[t - d] : 0;
        __syncthreads();
        tmp[t] += u;
        __syncthreads();
    }
    if (t < NBUCK) bsum[t] = tmp[t] - v;      // bucket exclusive prefix
}

__global__ void __launch_bounds__(256) k_part(const int* __restrict__ ei,
                                              const int* __restrict__ gloc,
                                              const int* __restrict__ bsum,
                                              uint* __restrict__ epk) {
    __shared__ int cur[NBUCK];
    int t = threadIdx.x;
    for (int i = t; i < NBUCK; i += 256)
        cur[i] = gloc[i * CB + blockIdx.x] + bsum[i];
    __syncthreads();
    int e0 = blockIdx.x * CHUNK;
    for (int i = t; i < CHUNK; i += 256) {
        int d = ei[N_EDGES + e0 + i];
        int s = ei[e0 + i];
        int p = atomicAdd(&cur[d >> 9], 1);
        epk[p] = ((uint)s << 9) | (uint)(d & 511);
    }
}

__global__ void __launch_bounds__(512) k_rank(const uint* __restrict__ epk,
                                              const int* __restrict__ bsum,
                                              int* __restrict__ offs,
                                              int* __restrict__ ssrc) {
    __shared__ int dcnt[W_BUCK];
    __shared__ int tmp[W_BUCK];
    __shared__ int cur[W_BUCK];
    int b = blockIdx.x, t = threadIdx.x;
    dcnt[t] = 0;
    __syncthreads();
    int s0 = bsum[b];
    int s1 = (b + 1 < NBUCK) ? bsum[b + 1] : N_EDGES;
    for (int i = s0 + t; i < s1; i += 512)
        atomicAdd(&dcnt[epk[i] & 511u], 1);
    __syncthreads();
    int v = dcnt[t];
    tmp[t] = v;
    __syncthreads();
    #pragma unroll
    for (int d = 1; d < 512; d <<= 1) {
        int u = (t >= d) ? tmp[t - d] : 0;
        __syncthreads();
        tmp[t] += u;
        __syncthreads();
    }
    int start = s0 + tmp[t] - v;               // exclusive prefix
    int node = b * W_BUCK + t;
    if (node <= N_NODES) offs[node] = start;   // node==N_NODES: writes offs end
    cur[t] = start;
    __syncthreads();
    for (int i = s0 + t; i < s1; i += 512) {
        uint u = epk[i];
        int p = atomicAdd(&cur[u & 511u], 1);
        ssrc[p] = (int)(u >> 9);
    }
}

// ---- graph segment boundaries (batch is sorted) ----------------------------

__global__ void k_bound(const int* __restrict__ batch, int* __restrict__ gstart) {
    int i = blockIdx.x * 256 + threadIdx.x;
    if (i >= N_NODES) return;
    int b = batch[i];
    if (i == 0) {
        for (int g = 0; g <= b; ++g) gstart[g] = 0;
    } else {
        int p = batch[i - 1];
        if (p != b) for (int g = p + 1; g <= b; ++g) gstart[g] = i;
    }
    if (i == N_NODES - 1) {
        for (int g = b + 1; g <= NUM_GRAPHS; ++g) gstart[g] = N_NODES;
    }
}

// ---- weight packs -----------------------------------------------------------

// layer 2: Wcat[f][0:128]=W2l[f][:], Wcat[f][128:256]=W2r[f][:], bf16
__global__ void k_packbf(const float* __restrict__ Wl, const float* __restrict__ Wr,
                         ushort* __restrict__ Wcat) {
    int i = blockIdx.x * 256 + threadIdx.x;    // 16384 exact
    int f = i >> 7, k = i & 127;
    Wcat[f * 256 + k]       = f2bf(Wl[i]);
    Wcat[f * 256 + 128 + k] = f2bf(Wr[i]);
}

// layer 1: Wcat1[f][32] bf16: k<8 -> W1r[f][k], 8..15 -> W1l[f][k-8], rest 0
__global__ void k_packbf1(const float* __restrict__ W1l, const float* __restrict__ W1r,
                          ushort* __restrict__ Wcat1) {
    int i = blockIdx.x * 256 + threadIdx.x;    // 4096 exact
    int f = i >> 5, k = i & 31;
    float v = (k < 8) ? W1r[f * 8 + k] : ((k < 16) ? W1l[f * 8 + (k - 8)] : 0.f);
    Wcat1[i] = f2bf(v);
}

// ---- layer 1 ---------------------------------------------------------------

// xa[n][32] bf16 = [x[n] (8) | mean_j x[src] (8) | zeros (16)]  — one 64B line
__global__ void k_agg1(const float* __restrict__ x, const int* __restrict__ offs,
                       const int* __restrict__ ssrc, ushort* __restrict__ xa) {
    int n = blockIdx.x * 256 + threadIdx.x;
    if (n >= N_NODES) return;
    int s0 = offs[n], s1 = offs[n + 1];
    float a0=0,a1=0,a2=0,a3=0,a4=0,a5=0,a6=0,a7=0;
    int j = s0;
    for (; j + 3 < s1; j += 4) {               // 8 gathers in flight
        int sa = ssrc[j], sb = ssrc[j+1], sc = ssrc[j+2], sd = ssrc[j+3];
        const float4* pa = (const float4*)(x + (size_t)sa * 8);
        const float4* pb = (const float4*)(x + (size_t)sb * 8);
        const float4* pc = (const float4*)(x + (size_t)sc * 8);
        const float4* pd = (const float4*)(x + (size_t)sd * 8);
        float4 va0 = pa[0], va1 = pa[1], vb0 = pb[0], vb1 = pb[1];
        float4 vc0 = pc[0], vc1 = pc[1], vd0 = pd[0], vd1 = pd[1];
        a0 += (va0.x + vb0.x) + (vc0.x + vd0.x);
        a1 += (va0.y + vb0.y) + (vc0.y + vd0.y);
        a2 += (va0.z + vb0.z) + (vc0.z + vd0.z);
        a3 += (va0.w + vb0.w) + (vc0.w + vd0.w);
        a4 += (va1.x + vb1.x) + (vc1.x + vd1.x);
        a5 += (va1.y + vb1.y) + (vc1.y + vd1.y);
        a6 += (va1.z + vb1.z) + (vc1.z + vd1.z);
        a7 += (va1.w + vb1.w) + (vc1.w + vd1.w);
    }
    for (; j < s1; ++j) {
        const float4* xp = (const float4*)(x + (size_t)ssrc[j] * 8);
        float4 b0 = xp[0], b1 = xp[1];
        a0+=b0.x; a1+=b0.y; a2+=b0.z; a3+=b0.w;
        a4+=b1.x; a5+=b1.y; a6+=b1.z; a7+=b1.w;
    }
    int dg = s1 - s0;
    float inv = 1.0f / (float)(dg > 1 ? dg : 1);
    const float4* xp = (const float4*)(x + (size_t)n * 8);
    float4 x0 = xp[0], x1v = xp[1];
    ushort* row = xa + (size_t)n * 32;
    uint4 o0 = {pack2(x0.x, x0.y), pack2(x0.z, x0.w), pack2(x1v.x, x1v.y), pack2(x1v.z, x1v.w)};
    uint4 o1 = {pack2(a0*inv, a1*inv), pack2(a2*inv, a3*inv),
                pack2(a4*inv, a5*inv), pack2(a6*inv, a7*inv)};
    uint4 z = {0u, 0u, 0u, 0u};
    *(uint4*)(row)      = o0;
    *(uint4*)(row + 8)  = o1;
    *(uint4*)(row + 16) = z;
    *(uint4*)(row + 24) = z;
}

// h1bf = bf16(xa @ Wcat1^T + b1) via one MFMA per f-tile; fp32 BN stats fused.
__global__ void __launch_bounds__(256) k_lin1(
        const ushort* __restrict__ xa, const ushort* __restrict__ Wcat1,
        const float* __restrict__ b1, ushort* __restrict__ h1bf,
        float* __restrict__ stats) {
    __shared__ ushort sOut[64 * 140];          // stride 140: 4-quad conflict-free
    __shared__ float sred[256];
    int tid = threadIdx.x;
    int wave = tid >> 6, lane = tid & 63;
    int quad = lane >> 4, l16 = lane & 15;
    int n0 = blockIdx.x * 64;

    int node = n0 + wave * 16 + l16;
    int cn = (node < N_NODES) ? node : N_NODES - 1;  // clamp; stores masked below
    B8 ta;
    ta.u = *(const uint4*)(xa + (size_t)cn * 32 + quad * 8);

    #pragma unroll
    for (int nt = 0; nt < 8; ++nt) {
        int fb = nt * 16 + l16;
        B8 tb;
        tb.u = *(const uint4*)(Wcat1 + fb * 32 + quad * 8);
        f32x4 acc = {0.f, 0.f, 0.f, 0.f};
        acc = __builtin_amdgcn_mfma_f32_16x16x32_bf16(ta.s, tb.s, acc, 0, 0, 0);
        float bb = b1[fb];
        #pragma unroll
        for (int r = 0; r < 4; ++r) {
            int row = wave * 16 + quad * 4 + r;
            sOut[row * 140 + fb] = f2bf(acc[r] + bb);
        }
    }
    __syncthreads();

    #pragma unroll
    for (int p = 0; p < 4; ++p) {
        int row = p * 16 + (tid >> 4);
        int nd = n0 + row;
        if (nd < N_NODES) {
            int c0 = (tid & 15) * 8;
            uint4 v = *(const uint4*)&sOut[row * 140 + c0];
            *(uint4*)(h1bf + (size_t)nd * F + c0) = v;
        }
    }

    int f = tid & 127, half = tid >> 7;
    float s = 0.f, s2 = 0.f;
    for (int r = half * 32; r < half * 32 + 32; ++r) {
        if (n0 + r >= N_NODES) break;
        float v = bf2f(sOut[r * 140 + f]);
        s += v; s2 += v * v;
    }
    if (half) { sred[f] = s; sred[128 + f] = s2; }
    __syncthreads();
    if (!half) {
        s += sred[f]; s2 += sred[128 + f];
        atomicAdd(&stats[f], s);
        atomicAdd(&stats[F + f], s2);
    }
}

__global__ void k_bnfin(const float* __restrict__ stats, const float* __restrict__ gamma,
                        const float* __restrict__ beta, float* __restrict__ scsh) {
    int f = threadIdx.x;
    float mu  = stats[f] * (1.0f / N_NODES);
    float var = stats[F + f] * (1.0f / N_NODES) - mu * mu;
    float sc  = gamma[f] * rsqrtf(var + BN_EPS);
    scsh[f] = sc;
    scsh[F + f] = beta[f] - mu * sc;
}

// x1bf = bf16(relu(scale*h1 + shift));  x1f8 = fp8_e4m3(same) for the gather
__global__ void k_bnrelu(const ushort* __restrict__ h, const float* __restrict__ scsh,
                         ushort* __restrict__ x1bf, uchar* __restrict__ x1f8) {
    int i = blockIdx.x * 256 + threadIdx.x;      // N*128/8 = 1.6M exact
    int base = i * 8;
    int f = base & (F - 1);
    float4 sc0 = *(const float4*)(scsh + f);
    float4 sc1 = *(const float4*)(scsh + f + 4);
    float4 sh0 = *(const float4*)(scsh + F + f);
    float4 sh1 = *(const float4*)(scsh + F + f + 4);
    uint4 hv = *(const uint4*)(h + base);
    float v0 = fmaxf(0.f, bflo(hv.x)*sc0.x + sh0.x);
    float v1 = fmaxf(0.f, bfhi(hv.x)*sc0.y + sh0.y);
    float v2 = fmaxf(0.f, bflo(hv.y)*sc0.z + sh0.z);
    float v3 = fmaxf(0.f, bfhi(hv.y)*sc0.w + sh0.w);
    float v4 = fmaxf(0.f, bflo(hv.z)*sc1.x + sh1.x);
    float v5 = fmaxf(0.f, bfhi(hv.z)*sc1.y + sh1.y);
    float v6 = fmaxf(0.f, bflo(hv.w)*sc1.z + sh1.z);
    float v7 = fmaxf(0.f, bfhi(hv.w)*sc1.w + sh1.w);
    uint4 o = {pack2(v0,v1), pack2(v2,v3), pack2(v4,v5), pack2(v6,v7)};
    *(uint4*)(x1bf + base) = o;
    int p0 = __builtin_amdgcn_cvt_pk_fp8_f32(v0, v1, 0, false);
    p0     = __builtin_amdgcn_cvt_pk_fp8_f32(v2, v3, p0, true);
    int p1 = __builtin_amdgcn_cvt_pk_fp8_f32(v4, v5, 0, false);
    p1     = __builtin_amdgcn_cvt_pk_fp8_f32(v6, v7, p1, true);
    uint2 o8 = {(uint)p0, (uint)p1};
    *(uint2*)(x1f8 + base) = o8;
}

// ---- layer 2 ---------------------------------------------------------------

// agg2bf[n][f] = bf16(mean over in-edges of fp8 x1f8[src][f]); 8 thr x 16B/node
__global__ void __launch_bounds__(256) k_agg2(
        const uchar* __restrict__ x1f8, const int* __restrict__ offs,
        const int* __restrict__ ssrc, ushort* __restrict__ agg2bf) {
    int t = threadIdx.x;
    int n = blockIdx.x * 32 + (t >> 3);        // 32 nodes/block, N%32==0
    int c16 = (t & 7) * 16;                    // 16 features per thread
    int s0 = offs[n], s1 = offs[n + 1];
    float acc[16];
    #pragma unroll
    for (int i = 0; i < 16; ++i) acc[i] = 0.f;
    int j = s0;
    for (; j + 3 < s1; j += 4) {               // 4 gathers in flight
        int sa = ssrc[j], sb = ssrc[j+1], sc = ssrc[j+2], sd = ssrc[j+3];
        uint4 va = *(const uint4*)(x1f8 + (size_t)sa * F + c16);
        uint4 vb = *(const uint4*)(x1f8 + (size_t)sb * F + c16);
        uint4 vc = *(const uint4*)(x1f8 + (size_t)sc * F + c16);
        uint4 vd = *(const uint4*)(x1f8 + (size_t)sd * F + c16);
        acc4f8(acc,      va.x); acc4f8(acc + 4,  va.y);
        acc4f8(acc + 8,  va.z); acc4f8(acc + 12, va.w);
        acc4f8(acc,      vb.x); acc4f8(acc + 4,  vb.y);
        acc4f8(acc + 8,  vb.z); acc4f8(acc + 12, vb.w);
        acc4f8(acc,      vc.x); acc4f8(acc + 4,  vc.y);
        acc4f8(acc + 8,  vc.z); acc4f8(acc + 12, vc.w);
        acc4f8(acc,      vd.x); acc4f8(acc + 4,  vd.y);
        acc4f8(acc + 8,  vd.z); acc4f8(acc + 12, vd.w);
    }
    for (; j < s1; ++j) {
        uint4 v = *(const uint4*)(x1f8 + (size_t)ssrc[j] * F + c16);
        acc4f8(acc,      v.x); acc4f8(acc + 4,  v.y);
        acc4f8(acc + 8,  v.z); acc4f8(acc + 12, v.w);
    }
    int dg = s1 - s0;
    float inv = 1.0f / (float)(dg > 1 ? dg : 1);
    uint4 o0 = {pack2(acc[0]*inv,  acc[1]*inv),  pack2(acc[2]*inv,  acc[3]*inv),
                pack2(acc[4]*inv,  acc[5]*inv),  pack2(acc[6]*inv,  acc[7]*inv)};
    uint4 o1 = {pack2(acc[8]*inv,  acc[9]*inv),  pack2(acc[10]*inv, acc[11]*inv),
                pack2(acc[12]*inv, acc[13]*inv), pack2(acc[14]*inv, acc[15]*inv)};
    ushort* dst = agg2bf + (size_t)n * F + c16;
    *(uint4*)(dst)     = o0;
    *(uint4*)(dst + 8) = o1;
}

// h2 = agg2 @ W2l^T + b2 + x1 @ W2r^T via bf16 MFMA.
// B in LDS with rotation swizzle g(f,j)=f*32+((j+f)&31): conflict-free for
// both the staging write AND the compute read (bank group = (4ks+q+l16)%8).
// Each B read feeds 2 node-tiles (pair) -> LDS reads halved per MFMA.
// BEST MEASURED CONFIG (r14 counters: 47.6 us, VGPR 124, conflicts 200K).
__device__ inline int gSw(int f, int j) { return (f << 5) | ((j + f) & 31); }

__global__ void __launch_bounds__(256, 2) k_lin2(
        const ushort* __restrict__ agg2bf, const ushort* __restrict__ x1bf,
        const ushort* __restrict__ Wcat, const float* __restrict__ b2,
        ushort* __restrict__ h2bf, float* __restrict__ stats) {
    __shared__ ushort sB[4096 * 8];            // 64 KB, swizzled granules
    int tid = threadIdx.x;
    int wave = tid >> 6, lane = tid & 63;
    int quad = lane >> 4, l16 = lane & 15;
    int f0 = wave * 32 + l16;
    int f1 = f0 + 16;

    // stage Wcat -> LDS (coalesced global; swizzled conflict-free LDS writes)
    #pragma unroll
    for (int it = 0; it < 16; ++it) {
        int c = it * 256 + tid;                // Wcat 16B-granule index
        int f = c >> 5, j = c & 31;
        uint4 v = *(const uint4*)(Wcat + (size_t)c * 8);
        *(uint4*)&sB[gSw(f, j) * 8] = v;
    }
    __syncthreads();

    float bb0 = b2[f0], bb1 = b2[f1];
    float s0 = 0.f, s0q = 0.f, s1 = 0.f, s1q = 0.f;
    int n0 = blockIdx.x * 128;

    s16x8 aA[2][8], aB[2][8];
    auto loadPair = [&](s16x8 (*a)[8], int nb) {
        #pragma unroll
        for (int mt = 0; mt < 2; ++mt) {
            int an = nb + mt * 16 + l16;
            if (an >= N_NODES) an = N_NODES - 1;   // clamp; stores masked below
            #pragma unroll
            for (int ks = 0; ks < 8; ++ks) {
                const ushort* src = (ks < 4) ? agg2bf : x1bf;
                B8 tm;
                tm.u = *(const uint4*)(src + (size_t)an * F + (ks & 3) * 32 + quad * 8);
                a[mt][ks] = tm.s;
            }
        }
    };
    auto computePair = [&](s16x8 (*a)[8], int nb) {
        f32x4 acc00 = {0,0,0,0}, acc01 = {0,0,0,0};
        f32x4 acc10 = {0,0,0,0}, acc11 = {0,0,0,0};
        #pragma unroll
        for (int ks = 0; ks < 8; ++ks) {
            int j = (ks << 2) + quad;
            B8 tb0, tb1;
            tb0.u = *(const uint4*)&sB[gSw(f0, j) * 8];
            tb1.u = *(const uint4*)&sB[gSw(f1, j) * 8];
            acc00 = __builtin_amdgcn_mfma_f32_16x16x32_bf16(a[0][ks], tb0.s, acc00, 0, 0, 0);
            acc01 = __builtin_amdgcn_mfma_f32_16x16x32_bf16(a[0][ks], tb1.s, acc01, 0, 0, 0);
            acc10 = __builtin_amdgcn_mfma_f32_16x16x32_bf16(a[1][ks], tb0.s, acc10, 0, 0, 0);
            acc11 = __builtin_amdgcn_mfma_f32_16x16x32_bf16(a[1][ks], tb1.s, acc11, 0, 0, 0);
        }
        #pragma unroll
        for (int r = 0; r < 4; ++r) {          // C: row=quad*4+r (node), col (f)
            int node0 = nb + quad * 4 + r;
            int node1 = node0 + 16;
            if (node0 < N_NODES) {
                float v0 = acc00[r] + bb0, v1 = acc01[r] + bb1;
                h2bf[(size_t)node0 * F + f0] = f2bf(v0);
                h2bf[(size_t)node0 * F + f1] = f2bf(v1);
                s0 += v0; s0q += v0 * v0;
                s1 += v1; s1q += v1 * v1;
            }
            if (node1 < N_NODES) {
                float v0 = acc10[r] + bb0, v1 = acc11[r] + bb1;
                h2bf[(size_t)node1 * F + f0] = f2bf(v0);
                h2bf[(size_t)node1 * F + f1] = f2bf(v1);
                s0 += v0; s0q += v0 * v0;
                s1 += v1; s1q += v1 * v1;
            }
        }
    };

    loadPair(aA, n0);
    #pragma unroll 1
    for (int p = 0; p < 2; ++p) {              // 4 pairs (32 nodes each), pipelined
        int nb = n0 + p * 64;
        loadPair(aB, nb + 32);
        computePair(aA, nb);
        if (p < 1) loadPair(aA, nb + 64);
        computePair(aB, nb + 32);
    }

    // reduce across the 4 quads (same f), then one atomic per f per block
    s0  += __shfl_xor(s0, 16);  s0  += __shfl_xor(s0, 32);
    s0q += __shfl_xor(s0q, 16); s0q += __shfl_xor(s0q, 32);
    s1  += __shfl_xor(s1, 16);  s1  += __shfl_xor(s1, 32);
    s1q += __shfl_xor(s1q, 16); s1q += __shfl_xor(s1q, 32);
    if (quad == 0) {
        atomicAdd(&stats[f0], s0);
        atomicAdd(&stats[F + f0], s0q);
        atomicAdd(&stats[f1], s1);
        atomicAdd(&stats[F + f1], s1q);
    }
}

// ---- pooling ---------------------------------------------------------------

__global__ void k_pool(const ushort* __restrict__ x1bf, const ushort* __restrict__ h2bf,
                       const float* __restrict__ scsh2, const int* __restrict__ batch,
                       float* __restrict__ outacc) {
    int f = threadIdx.x;
    int n0 = blockIdx.x * 128;
    int n1 = min(n0 + 128, N_NODES);
    float sc = scsh2[f], sh = scsh2[F + f];
    float acc = 0.f;
    int curg = batch[n0];
    for (int n = n0; n < n1; ++n) {
        int g = batch[n];
        if (g != curg) {
            atomicAdd(&outacc[curg * F + f], acc);
            acc = 0.f; curg = g;
        }
        float v1 = bf2f(x1bf[(size_t)n * F + f]);
        float v2 = fmaxf(0.f, bf2f(h2bf[(size_t)n * F + f]) * sc + sh);
        acc += v1 + v2;
    }
    atomicAdd(&outacc[curg * F + f], acc);
}

__global__ void k_out(const float* __restrict__ outacc, const int* __restrict__ gstart,
                      float* __restrict__ out) {
    int i = blockIdx.x * 256 + threadIdx.x;
    if (i >= NUM_GRAPHS * F) return;
    int g = i >> 7;
    int c = gstart[g + 1] - gstart[g];
    out[i] = outacc[i] / (float)(c > 1 ? c : 1);
}

}  // namespace

extern "C" void kernel_launch(void* const* d_in, const int* in_sizes, int n_in,
                              void* d_out, int out_size, void* d_ws, size_t ws_size,
                              hipStream_t stream) {
    const float* x     = (const float*)d_in[0];
    const int*   ei    = (const int*)d_in[1];    // [2, E]: row0 = src, row1 = dst
    const int*   batch = (const int*)d_in[2];
    const float* W1l   = (const float*)d_in[3];
    const float* b1    = (const float*)d_in[4];
    const float* W1r   = (const float*)d_in[5];
    const float* g1    = (const float*)d_in[6];
    const float* be1   = (const float*)d_in[7];
    const float* W2l   = (const float*)d_in[8];
    const float* b2    = (const float*)d_in[9];
    const float* W2r   = (const float*)d_in[10];
    const float* g2    = (const float*)d_in[11];
    const float* be2   = (const float*)d_in[12];
    float* out = (float*)d_out;

    char* w = (char*)d_ws;
    size_t o = 0;
    auto alloc = [&](size_t bytes) {
        void* p = w + o;
        o += (bytes + 511) & ~(size_t)511;
        return p;
    };
    int*    offs   = (int*)alloc((size_t)(N_NODES + 1) * 4);
    int*    gcount = (int*)alloc((size_t)NBUCK * CB * 4);
    int*    bsum   = (int*)alloc((size_t)NBUCK * 4);
    int*    ssrc   = (int*)alloc((size_t)N_EDGES * 4);
    uint*   epk    = (uint*)alloc((size_t)N_EDGES * 4);
    int*    gstart = (int*)alloc((NUM_GRAPHS + 1) * 4);
    float*  stats  = (float*)alloc(512 * 4);   // [s1,s1sq | s2,s2sq]
    float*  scsh   = (float*)alloc(512 * 4);   // [sc1,sh1 | sc2,sh2]
    ushort* Wcat   = (ushort*)alloc((size_t)F * 256 * 2);
    ushort* Wcat1  = (ushort*)alloc((size_t)F * 32 * 2);
    float*  outacc = (float*)alloc((size_t)NUM_GRAPHS * F * 4);
    ushort* xa     = (ushort*)alloc((size_t)N_NODES * 32 * 2);
    ushort* h1bf   = (ushort*)alloc((size_t)N_NODES * F * 2);
    ushort* x1bf   = (ushort*)alloc((size_t)N_NODES * F * 2);
    uchar*  x1f8   = (uchar*)alloc((size_t)N_NODES * F);
    ushort* agg2bf = (ushort*)alloc((size_t)N_NODES * F * 2);
    ushort* h2bf   = (ushort*)alloc((size_t)N_NODES * F * 2);

    hipMemsetAsync(stats,  0, 512 * 4, stream);
    hipMemsetAsync(outacc, 0, (size_t)NUM_GRAPHS * F * 4, stream);

    // CSR-by-dst: chunk bucket hist -> hierarchical scan -> partition -> rank
    k_histA<<<CB, 256, 0, stream>>>(ei, gcount);
    k_scanA<<<NBUCK, 512, 0, stream>>>(gcount, bsum);
    k_scanB<<<1, 256, 0, stream>>>(bsum);
    k_part <<<CB, 256, 0, stream>>>(ei, gcount, bsum, epk);
    k_rank <<<NBUCK, 512, 0, stream>>>(epk, bsum, offs, ssrc);
    k_bound<<<(N_NODES + 255) / 256, 256, 0, stream>>>(batch, gstart);
    k_packbf <<<64, 256, 0, stream>>>(W2l, W2r, Wcat);
    k_packbf1<<<16, 256, 0, stream>>>(W1l, W1r, Wcat1);

    // layer 1 (bf16 + MFMA; stats fused into k_lin1)
    k_agg1  <<<(N_NODES + 255) / 256, 256, 0, stream>>>(x, offs, ssrc, xa);
    k_lin1  <<<(N_NODES + 63) / 64, 256, 0, stream>>>(xa, Wcat1, b1, h1bf, stats);
    k_bnfin <<<1, 128, 0, stream>>>(stats, g1, be1, scsh);
    k_bnrelu<<<(N_NODES * F / 8) / 256, 256, 0, stream>>>(h1bf, scsh, x1bf, x1f8);

    // layer 2 (fp8 gather -> fp32 accum -> bf16 MFMA; B in swizzled LDS)
    k_agg2  <<<N_NODES / 32, 256, 0, stream>>>(x1f8, offs, ssrc, agg2bf);
    k_lin2  <<<(N_NODES + 127) / 128, 256, 0, stream>>>(agg2bf, x1bf, Wcat, b2,
                                                        h2bf, stats + 256);
    k_bnfin <<<1, 128, 0, stream>>>(stats + 256, g2, be2, scsh + 256);

    // residual + pool
    k_pool<<<(N_NODES + 127) / 128, 128, 0, stream>>>(x1bf, h2bf, scsh + 256, batch, outacc);
    k_out <<<(NUM_GRAPHS * F + 255) / 256, 256, 0, stream>>>(outacc, gstart, out);
}